// Round 2
// baseline (1805.087 us; speedup 1.0000x reference)
//
#include <hip/hip_runtime.h>
#include <math.h>

#define B_ 8
#define C_ 64
#define H_ 128
#define W_ 128
#define HW_ (H_*W_)

// ---------------------------------------------------------------------------
// Direct 3x3 conv, pad=1, stride=1, NCHW. Tile 32x8 pixels, CO_BLK output
// channels per block, 4 input channels staged per barrier round.
// Weights read via block-uniform indices -> scalar loads.
// ---------------------------------------------------------------------------
template<int CIN, int COUT, int CO_BLK, bool RELU>
__global__ __launch_bounds__(256)
void conv3x3_k(const float* __restrict__ in, const float* __restrict__ w,
               float* __restrict__ out)
{
    constexpr int TW = 32, TH = 8, CS = 4;
    __shared__ float tile[CS][TH+2][TW+2];
    const int tid = threadIdx.x;
    const int tx = tid & (TW-1);
    const int ty = tid / TW;
    const int tw = blockIdx.x & 3;        // W_/TW = 4
    const int th = blockIdx.x >> 2;       // H_/TH = 16
    const int co0 = blockIdx.y * CO_BLK;
    const int b  = blockIdx.z;
    const int w0 = tw*TW, h0 = th*TH;

    float acc[CO_BLK];
#pragma unroll
    for (int j=0;j<CO_BLK;j++) acc[j] = 0.f;

    const float* inb = in + (size_t)b*CIN*HW_;
    for (int ci0=0; ci0<CIN; ci0+=CS){
        __syncthreads();
        for (int idx=tid; idx<CS*(TH+2)*(TW+2); idx+=256){
            const int ci = idx/((TH+2)*(TW+2));
            const int rem = idx - ci*((TH+2)*(TW+2));
            const int r = rem/(TW+2), c = rem - r*(TW+2);
            const int iy = h0-1+r, ix = w0-1+c;
            float v = 0.f;
            if (iy>=0 && iy<H_ && ix>=0 && ix<W_)
                v = inb[(size_t)(ci0+ci)*HW_ + iy*W_ + ix];
            tile[ci][r][c] = v;
        }
        __syncthreads();
#pragma unroll
        for (int cc=0; cc<CS; ++cc){
            float xv[9];
#pragma unroll
            for (int r=0;r<3;r++)
#pragma unroll
                for (int s=0;s<3;s++)
                    xv[r*3+s] = tile[cc][ty+r][tx+s];
            const float* wci = w + ((size_t)co0*CIN + (ci0+cc))*9;
#pragma unroll
            for (int j=0;j<CO_BLK;j++){
                const float* wp = wci + (size_t)j*CIN*9;   // block-uniform -> s_load
#pragma unroll
                for (int k=0;k<9;k++)
                    acc[j] = fmaf(xv[k], wp[k], acc[j]);
            }
        }
    }
    const int oh = h0+ty, ow = w0+tx;
#pragma unroll
    for (int j=0;j<CO_BLK;j++){
        float v = acc[j];
        if (RELU) v = fmaxf(v, 0.f);
        out[(((size_t)b*COUT + (co0+j))*H_ + oh)*W_ + ow] = v;
    }
}

// ---------------------------------------------------------------------------
// wd[dk][o][c][k]  ->  wdT[dk][c*9+k][o]   (64-wide inner dim -> coalesced
// staging reads and stride-1 LDS writes in the deform kernel)
// ---------------------------------------------------------------------------
__global__ __launch_bounds__(256)
void transpose_wd_k(const float* __restrict__ wd, float* __restrict__ wdT)
{
    const int idx = blockIdx.x*256 + threadIdx.x;   // idx = (dk*576+ck)*64+o
    if (idx >= 2*576*64) return;
    const int o = idx & 63;
    const int rest = idx >> 6;
    const int dk = rest / 576;
    const int ck = rest - dk*576;
    const int c = ck/9, k = ck - c*9;
    wdT[idx] = wd[(((size_t)dk*64 + o)*64 + c)*9 + k];
}

// ---------------------------------------------------------------------------
// Fused: deformable conv (both dk) + 2-way softmax attention + weighted sum.
// Block = 64 consecutive pixels (one row segment) x all 64 output channels.
// Bilinear meta (addresses + folded mask*weights) computed ONCE per (k,px),
// shared across all 64 channels. Each thread: 4 px x 4 co register tile.
// ---------------------------------------------------------------------------
__global__ __launch_bounds__(256)
void deform_att_k(const float* __restrict__ x, const float* __restrict__ off,
                  const float* __restrict__ att, const float* __restrict__ wdT,
                  float* __restrict__ out)
{
    __shared__ __align__(16) int   mA [576];     // corner00 address within channel
    __shared__ __align__(16) int   mDx[576];     // x step to corner x1 (0/1)
    __shared__ __align__(16) int   mDr[576];     // row step to corner y1 (0/W_)
    __shared__ __align__(16) float mW0[576];     // w(y0,x0)  (masks folded)
    __shared__ __align__(16) float mW1[576];     // w(y0,x1)
    __shared__ __align__(16) float mW2[576];     // w(y1,x0)
    __shared__ __align__(16) float mW3[576];     // w(y1,x1)
    __shared__ __align__(16) float samp[72][64]; // [cl*9+k][px]
    __shared__ __align__(16) float wdL [72][64]; // [cl*9+k][o]

    const int tid = threadIdx.x;
    const int b   = blockIdx.z;
    const int oh  = blockIdx.y;
    const int ow0 = blockIdx.x * 64;
    const int px0 = (tid & 15) * 4;
    const int o0  = (tid >> 4) * 4;
    const float* xb = x + (size_t)b*C_*HW_;

    float outa[4][4];
#pragma unroll
    for (int i=0;i<4;i++)
#pragma unroll
        for (int j=0;j<4;j++) outa[i][j] = 0.f;

    for (int dk=0; dk<2; ++dk){
        // ---- bilinear meta, shared across channels (576 = 9 taps x 64 px) ----
        for (int e=tid; e<576; e+=256){
            const int k = e >> 6, px = e & 63;
            const float oy = off[(((size_t)b*36 + dk*18 + 2*k  )*H_ + oh)*W_ + ow0 + px];
            const float ox = off[(((size_t)b*36 + dk*18 + 2*k+1)*H_ + oh)*W_ + ow0 + px];
            const float py  = (float)(oh  - 1 + (k/3))        + oy;
            const float pxx = (float)(ow0 + px - 1 + (k%3))   + ox;
            const float y0f = floorf(py), x0f = floorf(pxx);
            const float ay = py - y0f, ax = pxx - x0f;
            const int y0 = (int)y0f, x0 = (int)x0f;
            const int y1 = y0 + 1,   x1 = x0 + 1;
            const float my0 = (y0 >= 0 && y0 < H_) ? 1.f : 0.f;
            const float my1 = (y1 >= 0 && y1 < H_) ? 1.f : 0.f;
            const float mx0 = (x0 >= 0 && x0 < W_) ? 1.f : 0.f;
            const float mx1 = (x1 >= 0 && x1 < W_) ? 1.f : 0.f;
            const int y0c = min(max(y0,0),H_-1), y1c = min(max(y1,0),H_-1);
            const int x0c = min(max(x0,0),W_-1), x1c = min(max(x1,0),W_-1);
            const float wy0 = my0*(1.f-ay), wy1 = my1*ay;
            const float wx0 = mx0*(1.f-ax), wx1 = mx1*ax;
            mA [e] = y0c*W_ + x0c;
            mDx[e] = x1c - x0c;            // 0 or 1
            mDr[e] = (y1c - y0c)*W_;       // 0 or W_
            mW0[e] = wy0*wx0;
            mW1[e] = wy0*wx1;
            mW2[e] = wy1*wx0;
            mW3[e] = wy1*wx1;
        }

        float acc[4][4];
#pragma unroll
        for (int i=0;i<4;i++)
#pragma unroll
            for (int j=0;j<4;j++) acc[i][j] = 0.f;

        for (int c8=0; c8<8; ++c8){
            __syncthreads();   // meta visible (c8==0); prev einsum done (c8>0)
            // ---- stage wd chunk: coalesced read, stride-1 LDS write ----
            for (int idx=tid; idx<72*64; idx+=256){
                const int o = idx & 63, ck = idx >> 6;
                wdL[ck][o] = wdT[((size_t)dk*576 + c8*72 + ck)*64 + o];
            }
            // ---- stage sampled tile: 4-px quads, vector meta reads ----
            for (int idx=tid; idx<72*16; idx+=256){
                const int ck = idx >> 4, pq = idx & 15;
                const int cl = ck/9;
                const int k  = ck - cl*9;
                const int e0 = k*64 + pq*4;
                const float* xc = xb + (size_t)(c8*8+cl)*HW_;
                const int4   a  = *(const int4*  )&mA [e0];
                const int4   dx = *(const int4*  )&mDx[e0];
                const int4   dr = *(const int4*  )&mDr[e0];
                const float4 w0 = *(const float4*)&mW0[e0];
                const float4 w1 = *(const float4*)&mW1[e0];
                const float4 w2 = *(const float4*)&mW2[e0];
                const float4 w3 = *(const float4*)&mW3[e0];
                float4 s;
                s.x = w0.x*xc[a.x] + w1.x*xc[a.x+dx.x] + w2.x*xc[a.x+dr.x] + w3.x*xc[a.x+dr.x+dx.x];
                s.y = w0.y*xc[a.y] + w1.y*xc[a.y+dx.y] + w2.y*xc[a.y+dr.y] + w3.y*xc[a.y+dr.y+dx.y];
                s.z = w0.z*xc[a.z] + w1.z*xc[a.z+dx.z] + w2.z*xc[a.z+dr.z] + w3.z*xc[a.z+dr.z+dx.z];
                s.w = w0.w*xc[a.w] + w1.w*xc[a.w+dx.w] + w2.w*xc[a.w+dr.w] + w3.w*xc[a.w+dr.w+dx.w];
                *(float4*)&samp[ck][pq*4] = s;
            }
            __syncthreads();
            // ---- einsum partial: 4px x 4o per thread ----
#pragma unroll
            for (int ck=0; ck<72; ++ck){
                const float4 s4 = *(const float4*)&samp[ck][px0];
                const float4 w4 = *(const float4*)&wdL [ck][o0];
                const float s[4] = {s4.x, s4.y, s4.z, s4.w};
                const float wv[4] = {w4.x, w4.y, w4.z, w4.w};
#pragma unroll
                for (int i=0;i<4;i++)
#pragma unroll
                    for (int j=0;j<4;j++)
                        acc[i][j] = fmaf(s[i], wv[j], acc[i][j]);
            }
        }
        // ---- softmax attention factor + accumulate ----
#pragma unroll
        for (int j=0;j<4;j++){
            const int o = o0 + j;
            const float4 as4 = *(const float4*)&att[(((size_t)b*128 + dk*64     + o)*H_ + oh)*W_ + ow0 + px0];
            const float4 ao4 = *(const float4*)&att[(((size_t)b*128 + (1-dk)*64 + o)*H_ + oh)*W_ + ow0 + px0];
            const float as[4] = {as4.x, as4.y, as4.z, as4.w};
            const float ao[4] = {ao4.x, ao4.y, ao4.z, ao4.w};
#pragma unroll
            for (int i=0;i<4;i++){
                const float f = 1.f / (1.f + __expf(ao[i] - as[i]));
                outa[i][j] = fmaf(acc[i][j], f, outa[i][j]);
            }
        }
    }
    // write output: 4 co rows x 4 consecutive px
#pragma unroll
    for (int j=0;j<4;j++){
        const float4 v = make_float4(outa[0][j], outa[1][j], outa[2][j], outa[3][j]);
        *(float4*)&out[(((size_t)b*64 + (o0+j))*H_ + oh)*W_ + ow0 + px0] = v;
    }
}

// ---------------------------------------------------------------------------
extern "C" void kernel_launch(void* const* d_in, const int* in_sizes, int n_in,
                              void* d_out, int out_size, void* d_ws, size_t ws_size,
                              hipStream_t stream)
{
    const float* x  = (const float*)d_in[0];
    const float* w1 = (const float*)d_in[1];
    const float* w2 = (const float*)d_in[2];
    const float* w3 = (const float*)d_in[3];
    const float* wa = (const float*)d_in[4];
    const float* wd = (const float*)d_in[5];
    float* out = (float*)d_out;

    float* ws   = (float*)d_ws;
    float* wdT  = ws;                 // 2*576*64      =    73728 floats
    float* m1   = wdT + 73728;        // 8*64*128*128  =  8388608
    float* m2   = m1 + 8388608;       // 8388608
    float* offs = m2 + 8388608;       // 8*36*128*128  =  4718592
    float* att  = m1;                 // reuse m1+m2 region (16777216 floats)

    const dim3 blk(256);
    transpose_wd_k<<<dim3(288), blk, 0, stream>>>(wd, wdT);
    // m1 = relu(conv(x, w1))
    conv3x3_k<64, 64, 32, true ><<<dim3(64, 2, 8), blk, 0, stream>>>(x,  w1, m1);
    // m2 = relu(conv(m1, w2))
    conv3x3_k<64, 64, 32, true ><<<dim3(64, 2, 8), blk, 0, stream>>>(m1, w2, m2);
    // offsets = conv(m2, w3)
    conv3x3_k<64, 36, 36, false><<<dim3(64, 1, 8), blk, 0, stream>>>(m2, w3, offs);
    // att = conv(x, wa)   (overwrites m1/m2 region -- both already consumed)
    conv3x3_k<64,128, 32, false><<<dim3(64, 4, 8), blk, 0, stream>>>(x,  wa, att);
    // fused deform conv + softmax attention + weighted sum
    deform_att_k<<<dim3(2, 128, 8), blk, 0, stream>>>(x, offs, att, wdT, out);
}

// Round 3
// 1630.955 us; speedup vs baseline: 1.1068x; 1.1068x over previous
//
#include <hip/hip_runtime.h>
#include <hip/hip_bf16.h>
#include <math.h>

#define B_ 8
#define C_ 64
#define H_ 128
#define W_ 128
#define HW_ (H_*W_)

typedef __attribute__((ext_vector_type(8))) short bf16x8;   // 8 bf16 = 4 VGPRs
typedef __attribute__((ext_vector_type(4))) float f32x4;    // MFMA acc frag

// ---------------------------------------------------------------------------
// Direct 3x3 conv, pad=1, stride=1, NCHW. Tile 32x8 pixels, CO_BLK output
// channels per block. Weights read via block-uniform indices -> scalar loads.
// (R1 version -- measured faster than the CS=4 variant.)
// ---------------------------------------------------------------------------
template<int CIN, int COUT, int CO_BLK, bool RELU>
__global__ __launch_bounds__(256)
void conv3x3_k(const float* __restrict__ in, const float* __restrict__ w,
               float* __restrict__ out)
{
    constexpr int TW = 32, TH = 8;
    __shared__ float tile[TH+2][TW+2];
    const int tid = threadIdx.x;
    const int tx = tid & (TW-1);
    const int ty = tid / TW;
    const int tw = blockIdx.x & 3;        // W_/TW = 4
    const int th = blockIdx.x >> 2;       // H_/TH = 16
    const int co0 = blockIdx.y * CO_BLK;
    const int b  = blockIdx.z;
    const int w0 = tw*TW, h0 = th*TH;

    float acc[CO_BLK];
#pragma unroll
    for (int j=0;j<CO_BLK;j++) acc[j] = 0.f;

    const float* inb = in + (size_t)b*CIN*HW_;
    for (int ci=0; ci<CIN; ++ci){
        __syncthreads();
        const float* inc = inb + (size_t)ci*HW_;
        for (int idx=tid; idx<(TH+2)*(TW+2); idx+=256){
            const int r = idx/(TW+2), c = idx - r*(TW+2);
            const int iy = h0-1+r, ix = w0-1+c;
            float v = 0.f;
            if (iy>=0 && iy<H_ && ix>=0 && ix<W_) v = inc[iy*W_+ix];
            tile[r][c] = v;
        }
        __syncthreads();
        float xv[9];
#pragma unroll
        for (int r=0;r<3;r++)
#pragma unroll
            for (int s=0;s<3;s++)
                xv[r*3+s] = tile[ty+r][tx+s];
        const float* wci = w + ((size_t)co0*CIN + ci)*9;
#pragma unroll
        for (int j=0;j<CO_BLK;j++){
            const float* wp = wci + (size_t)j*CIN*9;   // block-uniform -> s_load
#pragma unroll
            for (int k=0;k<9;k++)
                acc[j] = fmaf(xv[k], wp[k], acc[j]);
        }
    }
    const int oh = h0+ty, ow = w0+tx;
#pragma unroll
    for (int j=0;j<CO_BLK;j++){
        float v = acc[j];
        if (RELU) v = fmaxf(v, 0.f);
        out[(((size_t)b*COUT + (co0+j))*H_ + oh)*W_ + ow] = v;
    }
}

// ---------------------------------------------------------------------------
// wd fp32 [dk][o][c][kh][kw] -> bf16, same layout (= [dk*64+o][576] rows).
// ---------------------------------------------------------------------------
__global__ __launch_bounds__(256)
void cast_wd_k(const float* __restrict__ wd, __hip_bfloat16* __restrict__ wd16)
{
    const int i = blockIdx.x*256 + threadIdx.x;
    if (i < 2*64*576) wd16[i] = __float2bfloat16(wd[i]);
}

// ---------------------------------------------------------------------------
// Fused deformable conv (both dk, bf16 MFMA einsum) + softmax attention.
// Block = 64 px (one row segment) x 64 co. 4 waves; wave w owns px [16w,16w+16).
// K = 576 (= c*9+k), chunked by 64. Bilinear meta shared across channels.
//   A = wd  [co][k]  (M=co),  B = samp [px][k] (N=px)  -> D[co][px],
//   lane: px = lane&15 (coalesced epilogue), co = g*16 + (lane>>4)*4 + reg.
// ---------------------------------------------------------------------------
__global__ __launch_bounds__(256, 4)
void deform_att_k(const float* __restrict__ x, const float* __restrict__ off,
                  const float* __restrict__ att, const __hip_bfloat16* __restrict__ wd16,
                  float* __restrict__ out)
{
    __shared__ __align__(16) int4   metaI[9*65];   // (a00, dx, drow, -) stride-65 pad
    __shared__ __align__(16) float4 metaW[9*65];   // (w00, w01, w10, w11)
    __shared__ __align__(16) __hip_bfloat16 sampA[64][72];  // [px][ck]  144B rows
    __shared__ __align__(16) __hip_bfloat16 wdB [64][72];   // [co][ck]

    const int tid  = threadIdx.x;
    const int lane = tid & 63, wid = tid >> 6;
    const int l15  = lane & 15, khi = lane >> 4;
    const int b = blockIdx.z, oh = blockIdx.y, ow0 = blockIdx.x * 64;
    const float* xb = x + (size_t)b*C_*HW_;

    f32x4 acc[2][4];
    const f32x4 vzero = {0.f, 0.f, 0.f, 0.f};
#pragma unroll
    for (int d=0; d<2; ++d)
#pragma unroll
        for (int g=0; g<4; ++g) acc[d][g] = vzero;

#pragma unroll
    for (int dk=0; dk<2; ++dk){
        // ---- bilinear meta, shared across all 64 channels (9 taps x 64 px) ----
        for (int e=tid; e<576; e+=256){
            const int k = e >> 6, px = e & 63;
            const float oy = off[(((size_t)b*36 + dk*18 + 2*k  )*H_ + oh)*W_ + ow0 + px];
            const float ox = off[(((size_t)b*36 + dk*18 + 2*k+1)*H_ + oh)*W_ + ow0 + px];
            const float py  = (float)(oh  - 1 + (k/3))      + oy;
            const float pxx = (float)(ow0 + px - 1 + (k%3)) + ox;
            const float y0f = floorf(py), x0f = floorf(pxx);
            const float ay = py - y0f, ax = pxx - x0f;
            const int y0 = (int)y0f, x0 = (int)x0f;
            const int y1 = y0 + 1,   x1 = x0 + 1;
            const float my0 = (y0 >= 0 && y0 < H_) ? 1.f : 0.f;
            const float my1 = (y1 >= 0 && y1 < H_) ? 1.f : 0.f;
            const float mx0 = (x0 >= 0 && x0 < W_) ? 1.f : 0.f;
            const float mx1 = (x1 >= 0 && x1 < W_) ? 1.f : 0.f;
            const int y0c = min(max(y0,0),H_-1), y1c = min(max(y1,0),H_-1);
            const int x0c = min(max(x0,0),W_-1), x1c = min(max(x1,0),W_-1);
            const float wy0 = my0*(1.f-ay), wy1 = my1*ay;
            const float wx0 = mx0*(1.f-ax), wx1 = mx1*ax;
            metaI[k*65+px] = make_int4(y0c*W_ + x0c, x1c - x0c, (y1c - y0c)*W_, 0);
            metaW[k*65+px] = make_float4(wy0*wx0, wy0*wx1, wy1*wx0, wy1*wx1);
        }

        for (int ch=0; ch<9; ++ch){
            __syncthreads();   // prev chunk's MFMA reads done; meta visible (ch==0)
            // ---- stage wd chunk: [64 co][64 ck] bf16, 32B/thread ----
            {
                const int o = tid >> 2, seg = tid & 3;
                const uint4* src = (const uint4*)&wd16[(size_t)(dk*64+o)*576 + ch*64 + seg*16];
                *(uint4*)&wdB[o][seg*16    ] = src[0];
                *(uint4*)&wdB[o][seg*16 + 8] = src[1];
            }
            // ---- stage sampled tile: lane owns one ck, 16 px ----
            {
                const int ck  = tid & 63;
                const int ckg = ch*64 + ck;
                const int kk  = ckg % 9;
                const int c   = ckg / 9;
                const float* xc = xb + (size_t)c*HW_;
#pragma unroll
                for (int r2=0; r2<4; ++r2){
                    const int pq = (tid>>6) + 4*r2;
#pragma unroll
                    for (int i=0;i<4;i++){
                        const int px = pq*4+i;
                        const int4   mi = metaI[kk*65+px];
                        const float4 mw = metaW[kk*65+px];
                        const float v = mw.x*xc[mi.x]
                                      + mw.y*xc[mi.x+mi.y]
                                      + mw.z*xc[mi.x+mi.z]
                                      + mw.w*xc[mi.x+mi.z+mi.y];
                        sampA[px][ck] = __float2bfloat16(v);
                    }
                }
            }
            __syncthreads();
            // ---- MFMA: D[co][px] += wd[co][k] * samp[px][k], K=64 ----
#pragma unroll
            for (int s=0; s<2; ++s){
                const bf16x8 bfr = *(const bf16x8*)&sampA[wid*16 + l15][s*32 + khi*8];
#pragma unroll
                for (int g=0; g<4; ++g){
                    const bf16x8 afr = *(const bf16x8*)&wdB[g*16 + l15][s*32 + khi*8];
                    acc[dk][g] = __builtin_amdgcn_mfma_f32_16x16x32_bf16(afr, bfr, acc[dk][g], 0, 0, 0);
                }
            }
        }
    }
    // ---- epilogue: softmax attention weights + write (coalesced in px) ----
    const int px = wid*16 + l15;
#pragma unroll
    for (int g=0; g<4; ++g){
#pragma unroll
        for (int r=0; r<4; ++r){
            const int co = g*16 + khi*4 + r;
            const float a0 = att[(((size_t)b*128      + co)*H_ + oh)*W_ + ow0 + px];
            const float a1 = att[(((size_t)b*128 + 64 + co)*H_ + oh)*W_ + ow0 + px];
            const float f0 = 1.f / (1.f + __expf(a1 - a0));
            out[(((size_t)b*64 + co)*H_ + oh)*W_ + ow0 + px] =
                acc[0][g][r]*f0 + acc[1][g][r]*(1.f - f0);
        }
    }
}

// ---------------------------------------------------------------------------
extern "C" void kernel_launch(void* const* d_in, const int* in_sizes, int n_in,
                              void* d_out, int out_size, void* d_ws, size_t ws_size,
                              hipStream_t stream)
{
    const float* x  = (const float*)d_in[0];
    const float* w1 = (const float*)d_in[1];
    const float* w2 = (const float*)d_in[2];
    const float* w3 = (const float*)d_in[3];
    const float* wa = (const float*)d_in[4];
    const float* wd = (const float*)d_in[5];
    float* out = (float*)d_out;

    float* ws = (float*)d_ws;
    __hip_bfloat16* wd16 = (__hip_bfloat16*)ws;   // 73728 bf16 = 36864 floats
    float* m1   = ws + 36864;         // 8*64*128*128  =  8388608 floats
    float* m2   = m1 + 8388608;       // 8388608
    float* offs = m2 + 8388608;       // 8*36*128*128  =  4718592
    float* att  = m1;                 // reuse m1+m2 region (16777216 floats)

    const dim3 blk(256);
    cast_wd_k<<<dim3(288), blk, 0, stream>>>(wd, wd16);
    // m1 = relu(conv(x, w1))
    conv3x3_k<64, 64, 32, true ><<<dim3(64, 2, 8), blk, 0, stream>>>(x,  w1, m1);
    // m2 = relu(conv(m1, w2))
    conv3x3_k<64, 64, 32, true ><<<dim3(64, 2, 8), blk, 0, stream>>>(m1, w2, m2);
    // offsets = conv(m2, w3)
    conv3x3_k<64, 36, 36, false><<<dim3(64, 1, 8), blk, 0, stream>>>(m2, w3, offs);
    // att = conv(x, wa)   (overwrites m1/m2 region -- both already consumed)
    conv3x3_k<64,128, 32, false><<<dim3(64, 4, 8), blk, 0, stream>>>(x,  wa, att);
    // fused deform conv (MFMA) + softmax attention
    deform_att_k<<<dim3(2, 128, 8), blk, 0, stream>>>(x, offs, att, wd16, out);
}

// Round 4
// 315.787 us; speedup vs baseline: 5.7161x; 5.1647x over previous
//
#include <hip/hip_runtime.h>
#include <hip/hip_bf16.h>
#include <math.h>

#define B_ 8
#define C_ 64
#define H_ 128
#define W_ 128
#define HW_ (H_*W_)
#define HP_ 130
#define WP_ 130
#define XPLANE_ (HP_*WP_*64)     // padded NHWC plane per batch (halfwords)

typedef __attribute__((ext_vector_type(8))) short bf16x8;
typedef __attribute__((ext_vector_type(4))) float f32x4;
typedef __attribute__((ext_vector_type(4))) unsigned int u32x4;

// ---------------------------------------------------------------------------
__global__ __launch_bounds__(256)
void zero_k(unsigned int* __restrict__ p, int n)
{
    for (int i = blockIdx.x*256 + threadIdx.x; i < n; i += gridDim.x*256)
        p[i] = 0u;
}

// ---------------------------------------------------------------------------
// x NCHW fp32 -> xTp padded NHWC bf16 (interior only; halo pre-zeroed).
// Block: 64-px row segment, all 64 channels. LDS transpose.
// ---------------------------------------------------------------------------
__global__ __launch_bounds__(256)
void xpose_x_k(const float* __restrict__ x, __hip_bfloat16* __restrict__ xTp)
{
    __shared__ float tile[64][65];
    const int tid = threadIdx.x;
    const int w0 = blockIdx.x*64, h = blockIdx.y, b = blockIdx.z;
    const float* xb = x + (size_t)b*64*HW_;
    for (int i = tid; i < 4096; i += 256){
        const int c = i >> 6, px = i & 63;
        tile[c][px] = xb[(size_t)c*HW_ + h*W_ + w0 + px];
    }
    __syncthreads();
    __hip_bfloat16* ob = xTp + (size_t)b*XPLANE_;
    for (int i = tid; i < 512; i += 256){
        const int px = i >> 3, cs = i & 7;
        union { bf16x8 v; __hip_bfloat16 h8[8]; } R;
#pragma unroll
        for (int j=0;j<8;j++) R.h8[j] = __float2bfloat16(tile[cs*8+j][px]);
        *(bf16x8*)&ob[((size_t)(h+1)*WP_ + (w0+px+1))*64 + cs*8] = R.v;
    }
}

// ---------------------------------------------------------------------------
// Weight transpose+cast: w fp32 [O][64][9] -> wT bf16 [9][OPAD][64]
// (rows o>=O pre-zeroed by zero_k where OPAD>O).
// ---------------------------------------------------------------------------
__global__ __launch_bounds__(256)
void cast_w_k(const float* __restrict__ w, __hip_bfloat16* __restrict__ wT,
              int O, int OPAD)
{
    const int idx = blockIdx.x*256 + threadIdx.x;
    if (idx >= 9*O*64) return;
    const int k = idx / (O*64);
    const int rem = idx - k*O*64;
    const int o = rem >> 6, c = rem & 63;
    wT[((size_t)k*OPAD + o)*64 + c] = __float2bfloat16(w[((size_t)o*64 + c)*9 + k]);
}

// ---------------------------------------------------------------------------
// Implicit-GEMM 3x3 conv via MFMA. Input: padded NHWC bf16. Per k-tap:
// A = weight tile [G*16 co][64 c] (LDS, XOR-swizzled), B = direct 16B NHWC
// loads at the tap-shifted position. D[co][px], px = wid*16 + (lane&15).
// ---------------------------------------------------------------------------
enum OutMode { OUT_NHWC_PAD_RELU, OUT_NCHW_F32, OUT_NCHW_BF16 };

template<int G, int CO_TOT, OutMode MODE>
__global__ __launch_bounds__(256)
void conv_mfma_k(const __hip_bfloat16* __restrict__ xT,
                 const __hip_bfloat16* __restrict__ wT, int o_total,
                 void* __restrict__ outp)
{
    __shared__ __hip_bfloat16 wA[64][64];
    const int tid = threadIdx.x, lane = tid & 63, wid = tid >> 6;
    const int l15 = lane & 15, khi = lane >> 4;
    const int ow0 = blockIdx.x*64, oh = blockIdx.y;
    const int b = blockIdx.z & 7, cob = blockIdx.z >> 3;
    const int px = wid*16 + l15;
    const __hip_bfloat16* xb = xT + (size_t)b*XPLANE_;

    f32x4 acc[G];
    const f32x4 vz = {0.f,0.f,0.f,0.f};
#pragma unroll
    for (int g=0; g<G; ++g) acc[g] = vz;

    for (int k=0; k<9; ++k){
        const int dy = k/3 - 1, dxk = k%3 - 1;
        __syncthreads();
        // stage A tile: G*16 rows x 64 c, 16B chunks, col8 ^= row&7 swizzle
        for (int i=tid; i<G*16*8; i+=256){
            const int o = i >> 3, cs = i & 7;
            *(bf16x8*)&wA[o][((cs ^ (o&7))*8)] =
                *(const bf16x8*)&wT[((size_t)k*o_total + cob*64 + o)*64 + cs*8];
        }
        __syncthreads();
        const int base = (((oh+1+dy)*WP_) + (ow0+px+1+dxk))*64;
#pragma unroll
        for (int s=0; s<2; ++s){
            const bf16x8 bfr = *(const bf16x8*)&xb[base + s*32 + khi*8];
            const int c8 = ((s*4 + khi) ^ (l15 & 7))*8;
#pragma unroll
            for (int g=0; g<G; ++g){
                const bf16x8 afr = *(const bf16x8*)&wA[g*16 + l15][c8];
                acc[g] = __builtin_amdgcn_mfma_f32_16x16x32_bf16(afr, bfr, acc[g], 0,0,0);
            }
        }
    }
    // ---- epilogue ----
    if (MODE == OUT_NHWC_PAD_RELU){
        __hip_bfloat16* ob = (__hip_bfloat16*)outp + (size_t)b*XPLANE_;
        const size_t orow = ((size_t)(oh+1)*WP_ + (ow0+px+1))*64;
#pragma unroll
        for (int g=0; g<G; ++g){
            union { short4 s4; __hip_bfloat16 h[4]; } o4;
#pragma unroll
            for (int r=0;r<4;r++) o4.h[r] = __float2bfloat16(fmaxf(acc[g][r], 0.f));
            *(short4*)&ob[orow + g*16 + khi*4] = o4.s4;
        }
    } else if (MODE == OUT_NCHW_F32){
        float* ob = (float*)outp;
#pragma unroll
        for (int g=0; g<G; ++g)
#pragma unroll
            for (int r=0;r<4;r++){
                const int co = cob*64 + g*16 + khi*4 + r;
                if (co < CO_TOT)
                    ob[(((size_t)b*CO_TOT + co)*H_ + oh)*W_ + ow0 + px] = acc[g][r];
            }
    } else {
        __hip_bfloat16* ob = (__hip_bfloat16*)outp;
#pragma unroll
        for (int g=0; g<G; ++g)
#pragma unroll
            for (int r=0;r<4;r++){
                const int co = cob*64 + g*16 + khi*4 + r;
                ob[(((size_t)b*CO_TOT + co)*H_ + oh)*W_ + ow0 + px] = __float2bfloat16(acc[g][r]);
            }
    }
}

// ---------------------------------------------------------------------------
// 4-corner bilinear blend of 8 consecutive channels (NHWC bf16) -> bf16x8.
// ---------------------------------------------------------------------------
__device__ __forceinline__ bf16x8 blend4(const __hip_bfloat16* __restrict__ xb,
                                         int a00, int dxo, int dro, float4 w)
{
    const u32x4 q00 = *(const u32x4*)(xb + a00);
    const u32x4 q01 = *(const u32x4*)(xb + a00 + dxo);
    const u32x4 q10 = *(const u32x4*)(xb + a00 + dro);
    const u32x4 q11 = *(const u32x4*)(xb + a00 + dro + dxo);
    union { bf16x8 v; __hip_bfloat16 h[8]; } R;
#pragma unroll
    for (int p=0;p<4;++p){
        const float l00 = __uint_as_float(q00[p]<<16), h00 = __uint_as_float(q00[p]&0xFFFF0000u);
        const float l01 = __uint_as_float(q01[p]<<16), h01 = __uint_as_float(q01[p]&0xFFFF0000u);
        const float l10 = __uint_as_float(q10[p]<<16), h10 = __uint_as_float(q10[p]&0xFFFF0000u);
        const float l11 = __uint_as_float(q11[p]<<16), h11 = __uint_as_float(q11[p]&0xFFFF0000u);
        R.h[2*p  ] = __float2bfloat16(w.x*l00 + w.y*l01 + w.z*l10 + w.w*l11);
        R.h[2*p+1] = __float2bfloat16(w.x*h00 + w.y*h01 + w.z*h10 + w.w*h11);
    }
    return R.v;
}

// ---------------------------------------------------------------------------
// Fused deformable conv (MFMA) + softmax attention. B-fragments built in
// registers from 16B NHWC corner gathers (8 ch/load). K-chunk = one tap
// (64 channels). Meta (corner addr + weights) computed once per dk in LDS.
// ---------------------------------------------------------------------------
__global__ __launch_bounds__(256)
void deform_att_k(const __hip_bfloat16* __restrict__ xT,
                  const float* __restrict__ off,
                  const __hip_bfloat16* __restrict__ att,
                  const __hip_bfloat16* __restrict__ wTd,   // [9][128][64]
                  float* __restrict__ out)
{
    __shared__ int4   mI[9][64];
    __shared__ float4 mW[9][64];
    __shared__ __hip_bfloat16 wA[64][64];
    const int tid = threadIdx.x, lane = tid & 63, wid = tid >> 6;
    const int l15 = lane & 15, khi = lane >> 4;
    const int ow0 = blockIdx.x*64, oh = blockIdx.y, b = blockIdx.z;
    const int px = wid*16 + l15;
    const __hip_bfloat16* xb = xT + (size_t)b*XPLANE_;

    f32x4 acc[2][4];
    const f32x4 vz = {0.f,0.f,0.f,0.f};
#pragma unroll
    for (int d=0; d<2; ++d)
#pragma unroll
        for (int g=0; g<4; ++g) acc[d][g] = vz;

    for (int dk=0; dk<2; ++dk){
        __syncthreads();   // prior dk's meta reads complete
        for (int e=tid; e<576; e+=256){
            const int k = e >> 6, p = e & 63;
            const float oy = off[(((size_t)b*36 + dk*18 + 2*k  )*H_ + oh)*W_ + ow0 + p];
            const float ox = off[(((size_t)b*36 + dk*18 + 2*k+1)*H_ + oh)*W_ + ow0 + p];
            const float py  = (float)(oh  - 1 + (k/3))      + oy;
            const float pxx = (float)(ow0 + p - 1 + (k%3))  + ox;
            const float y0f = floorf(py), x0f = floorf(pxx);
            const float ay = py - y0f, ax = pxx - x0f;
            const int y0 = (int)y0f, x0 = (int)x0f;
            const int y1 = y0 + 1,   x1 = x0 + 1;
            const float my0 = (y0 >= 0 && y0 < H_) ? 1.f : 0.f;
            const float my1 = (y1 >= 0 && y1 < H_) ? 1.f : 0.f;
            const float mx0 = (x0 >= 0 && x0 < W_) ? 1.f : 0.f;
            const float mx1 = (x1 >= 0 && x1 < W_) ? 1.f : 0.f;
            const int y0c = min(max(y0,0),H_-1), y1c = min(max(y1,0),H_-1);
            const int x0c = min(max(x0,0),W_-1), x1c = min(max(x1,0),W_-1);
            const float wy0 = my0*(1.f-ay), wy1 = my1*ay;
            const float wx0 = mx0*(1.f-ax), wx1 = mx1*ax;
            mI[k][p] = make_int4(((y0c+1)*WP_ + (x0c+1))*64,
                                 (x1c-x0c)*64, (y1c-y0c)*WP_*64, 0);
            mW[k][p] = make_float4(wy0*wx0, wy0*wx1, wy1*wx0, wy1*wx1);
        }
        for (int k=0; k<9; ++k){
            __syncthreads();   // wA reuse safe; meta visible (k==0)
            for (int i=tid; i<512; i+=256){
                const int o = i >> 3, cs = i & 7;
                *(bf16x8*)&wA[o][((cs ^ (o&7))*8)] =
                    *(const bf16x8*)&wTd[((size_t)k*128 + dk*64 + o)*64 + cs*8];
            }
            __syncthreads();
            const int4   mi  = mI[k][px];
            const float4 mwt = mW[k][px];
#pragma unroll
            for (int s=0; s<2; ++s){
                const bf16x8 bfr = blend4(xb, mi.x + s*32 + khi*8, mi.y, mi.z, mwt);
                const int c8 = ((s*4 + khi) ^ (l15 & 7))*8;
#pragma unroll
                for (int g=0; g<4; ++g){
                    const bf16x8 afr = *(const bf16x8*)&wA[g*16 + l15][c8];
                    acc[dk][g] = __builtin_amdgcn_mfma_f32_16x16x32_bf16(afr, bfr, acc[dk][g], 0,0,0);
                }
            }
        }
    }
    // ---- epilogue: softmax over the 2 dynamic branches + write ----
#pragma unroll
    for (int g=0; g<4; ++g)
#pragma unroll
        for (int r=0; r<4; ++r){
            const int co = g*16 + khi*4 + r;
            const float a0 = __bfloat162float(att[(((size_t)b*128      + co)*H_ + oh)*W_ + ow0 + px]);
            const float a1 = __bfloat162float(att[(((size_t)b*128 + 64 + co)*H_ + oh)*W_ + ow0 + px]);
            const float f0 = 1.f / (1.f + __expf(a1 - a0));
            out[(((size_t)b*64 + co)*H_ + oh)*W_ + ow0 + px] =
                acc[0][g][r]*f0 + acc[1][g][r]*(1.f - f0);
        }
}

// ---------------------------------------------------------------------------
extern "C" void kernel_launch(void* const* d_in, const int* in_sizes, int n_in,
                              void* d_out, int out_size, void* d_ws, size_t ws_size,
                              hipStream_t stream)
{
    const float* x  = (const float*)d_in[0];
    const float* w1 = (const float*)d_in[1];
    const float* w2 = (const float*)d_in[2];
    const float* w3 = (const float*)d_in[3];
    const float* wa = (const float*)d_in[4];
    const float* wd = (const float*)d_in[5];
    float* out = (float*)d_out;

    // ---- workspace layout (halfword units for bf16 regions) ----
    __hip_bfloat16* xTp  = (__hip_bfloat16*)d_ws;       // 8,652,800
    __hip_bfloat16* m1Tp = xTp  + (size_t)8652800;      // 8,652,800
    __hip_bfloat16* m2Tp = m1Tp + (size_t)8652800;      // 8,652,800
    __hip_bfloat16* wT1  = m2Tp + (size_t)8652800;      // 9*64*64   = 36864
    __hip_bfloat16* wT2  = wT1  + 36864;                // 36864
    __hip_bfloat16* wT3  = wT2  + 36864;                // 9*48*64   = 27648
    __hip_bfloat16* wTa  = wT3  + 27648;                // 9*128*64  = 73728
    __hip_bfloat16* wTd  = wTa  + 73728;                // 73728
    float*          offs = (float*)(wTd + 73728);       // 8*36*128*128 fp32
    __hip_bfloat16* att16 = m1Tp;   // aliases m1Tp+m2Tp (both dead by then)
    // total ws use ~71.3 MB

    const dim3 blk(256);
    // zero padded NHWC buffers (halos) + wT3 pad rows
    zero_k<<<dim3(2048), blk, 0, stream>>>((unsigned int*)xTp, 12979200);
    zero_k<<<dim3(54),   blk, 0, stream>>>((unsigned int*)wT3, 13824);
    // layout transforms
    xpose_x_k<<<dim3(2,128,8), blk, 0, stream>>>(x, xTp);
    cast_w_k<<<dim3(144), blk, 0, stream>>>(w1, wT1,  64,  64);
    cast_w_k<<<dim3(144), blk, 0, stream>>>(w2, wT2,  64,  64);
    cast_w_k<<<dim3(81),  blk, 0, stream>>>(w3, wT3,  36,  48);
    cast_w_k<<<dim3(288), blk, 0, stream>>>(wa, wTa, 128, 128);
    cast_w_k<<<dim3(288), blk, 0, stream>>>(wd, wTd, 128, 128);
    // conv chain (implicit-GEMM MFMA)
    conv_mfma_k<4,  64, OUT_NHWC_PAD_RELU><<<dim3(2,128,8),  blk, 0, stream>>>(xTp,  wT1,  64, m1Tp);
    conv_mfma_k<4,  64, OUT_NHWC_PAD_RELU><<<dim3(2,128,8),  blk, 0, stream>>>(m1Tp, wT2,  64, m2Tp);
    conv_mfma_k<3,  36, OUT_NCHW_F32     ><<<dim3(2,128,8),  blk, 0, stream>>>(m2Tp, wT3,  48, offs);
    conv_mfma_k<4, 128, OUT_NCHW_BF16    ><<<dim3(2,128,16), blk, 0, stream>>>(xTp,  wTa, 128, att16);
    // fused deformable conv + attention
    deform_att_k<<<dim3(2,128,8), blk, 0, stream>>>(xTp, offs, att16, wTd, out);
}